// Round 1
// baseline (4551.702 us; speedup 1.0000x reference)
//
#include <hip/hip_runtime.h>

// Decoder LSTM: B=32, T=511 steps, H=1024, 4H=4096, V=32000
// out = res[32][511][1024] ++ hT[32][1024] ++ cT[32][1024]  (fp32)

typedef __bf16 bf16;
typedef __bf16 bf16x4 __attribute__((ext_vector_type(4)));
typedef __bf16 bf16x8 __attribute__((ext_vector_type(8)));
typedef float f32x4 __attribute__((ext_vector_type(4)));

#define M_TOT 16352   // 511*32 rows of x_proj
#define RES_STRIDE 523264  // 511*1024
#define HT_OFF 16744448    // 32*511*1024
#define CT_OFF 16777216    // HT_OFF + 32768

// ---------- fp32 -> bf16 conversion (n4 = n/4 groups) ----------
__global__ void cvt_kernel(const float* __restrict__ src, bf16* __restrict__ dst, int n4) {
    int i = blockIdx.x * blockDim.x + threadIdx.x;
    if (i < n4) {
        float4 v = ((const float4*)src)[i];
        bf16x4 o;
        o[0] = (bf16)v.x; o[1] = (bf16)v.y; o[2] = (bf16)v.z; o[3] = (bf16)v.w;
        ((bf16x4*)dst)[i] = o;
    }
}

// ---------- init h (bf16) and c (fp32) state ----------
__global__ void init_state(const float* __restrict__ h0, const float* __restrict__ c0,
                           bf16* __restrict__ hbuf, float* __restrict__ cbuf) {
    int i = blockIdx.x * blockDim.x + threadIdx.x;
    if (i < 32768) {
        hbuf[i] = (bf16)h0[i];
        cbuf[i] = c0[i];
    }
}

// ---------- x_proj GEMM: P[m][j] = emb[tok(m)] . W_ih[j] + bias[j], bf16 out ----------
// 128x128 tile, 4 waves, each wave 64x64 via 4x4 frags of 16x16x32 MFMA.
__global__ __launch_bounds__(256) void gemm_xproj(
    const int* __restrict__ tgt, const bf16* __restrict__ emb,
    const bf16* __restrict__ wih, const float* __restrict__ bih,
    const float* __restrict__ bhh, bf16* __restrict__ P)
{
    __shared__ bf16 As[128 * 72];  // +8 pad per row (bank-conflict break)
    __shared__ bf16 Bs[128 * 72];
    __shared__ int tok[128];

    const int tid  = threadIdx.x;
    const int lane = tid & 63;
    const int wave = tid >> 6;
    const int wm = wave & 1, wn = wave >> 1;
    const int tileM = blockIdx.y * 128;
    const int tileN = blockIdx.x * 128;

    if (tid < 128) {
        int m = tileM + tid;
        int token = 0;
        if (m < M_TOT) {
            int t = m >> 5, b = m & 31;
            token = tgt[b * 512 + t];           // x = tgt[:, :511]
            if ((unsigned)token >= 32000u) token = 0;
        }
        tok[tid] = token;
    }
    __syncthreads();

    f32x4 acc[4][4] = {};

    for (int k0 = 0; k0 < 1024; k0 += 64) {
        #pragma unroll
        for (int i = 0; i < 4; ++i) {
            int chunk = i * 256 + tid;      // 0..1023
            int row = chunk >> 3;           // 0..127
            int kc  = (chunk & 7) * 8;      // 0..56
            const bf16* srcA = emb + (long)tok[row] * 1024 + k0 + kc;
            *(uint4*)&As[row * 72 + kc] = *(const uint4*)srcA;
            const bf16* srcB = wih + (long)(tileN + row) * 1024 + k0 + kc;
            *(uint4*)&Bs[row * 72 + kc] = *(const uint4*)srcB;
        }
        __syncthreads();
        #pragma unroll
        for (int kk = 0; kk < 64; kk += 32) {
            bf16x8 a[4], b[4];
            #pragma unroll
            for (int f = 0; f < 4; ++f) {
                a[f] = *(const bf16x8*)&As[(wm * 64 + f * 16 + (lane & 15)) * 72 + kk + (lane >> 4) * 8];
                b[f] = *(const bf16x8*)&Bs[(wn * 64 + f * 16 + (lane & 15)) * 72 + kk + (lane >> 4) * 8];
            }
            #pragma unroll
            for (int mf = 0; mf < 4; ++mf)
                #pragma unroll
                for (int nf = 0; nf < 4; ++nf)
                    acc[mf][nf] = __builtin_amdgcn_mfma_f32_16x16x32_bf16(a[mf], b[nf], acc[mf][nf], 0, 0, 0);
        }
        __syncthreads();
    }

    float bias[4];
    #pragma unroll
    for (int nf = 0; nf < 4; ++nf) {
        int j = tileN + wn * 64 + nf * 16 + (lane & 15);
        bias[nf] = bih[j] + bhh[j];
    }
    #pragma unroll
    for (int mf = 0; mf < 4; ++mf) {
        int mBase = tileM + wm * 64 + mf * 16 + ((lane >> 4) * 4);
        #pragma unroll
        for (int r = 0; r < 4; ++r) {
            int m = mBase + r;
            if (m < M_TOT) {
                #pragma unroll
                for (int nf = 0; nf < 4; ++nf) {
                    int j = tileN + wn * 64 + nf * 16 + (lane & 15);
                    P[(long)m * 4096 + j] = (bf16)(acc[mf][nf][r] + bias[nf]);
                }
            }
        }
    }
}

// ---------- one LSTM step: 64 blocks x 16 h-cols, all 4 gates per block ----------
__global__ __launch_bounds__(256) void lstm_step(
    const bf16* __restrict__ P, const bf16* __restrict__ whh,
    const bf16* __restrict__ hin, bf16* __restrict__ hout,
    float* __restrict__ cbuf, float* __restrict__ out, int t)
{
    // 64KB: h staged bf16 [32][1024], 16B-chunk XOR swizzle; aliased as gate
    // exchange fp32 [4][32][16] after the K loop.
    __shared__ bf16 hs[32 * 1024];

    const int tid  = threadIdx.x;
    const int lane = tid & 63;
    const int wave = tid >> 6;       // = gate index
    const int c0 = blockIdx.x * 16;  // h-column base

    #pragma unroll
    for (int i = 0; i < 16; ++i) {
        int chunk = i * 256 + tid;       // 0..4095 (16B chunks)
        int row = chunk >> 7;            // 0..31
        int cIn = chunk & 127;           // chunk within row
        *(uint4*)&hs[row * 1024 + ((cIn ^ (row & 7)) << 3)] =
            *(const uint4*)&hin[row * 1024 + (cIn << 3)];
    }
    __syncthreads();

    const int n = lane & 15;
    const int kg = lane >> 4;            // k-group 0..3
    const bf16* wrow = whh + ((long)(wave * 1024 + c0 + n)) * 1024 + kg * 8;

    f32x4 accA = {0.f, 0.f, 0.f, 0.f};
    f32x4 accB = {0.f, 0.f, 0.f, 0.f};
    const int m0 = n;          // rows 0..15 (A-frag m = lane&15)
    const int m1 = n + 16;     // rows 16..31

    #pragma unroll 4
    for (int kk = 0; kk < 1024; kk += 32) {
        bf16x8 bfr = *(const bf16x8*)(wrow + kk);
        int cA = (kk >> 3) + kg;   // 16B chunk index of this frag's k
        bf16x8 a0 = *(const bf16x8*)&hs[m0 * 1024 + ((cA ^ (m0 & 7)) << 3)];
        bf16x8 a1 = *(const bf16x8*)&hs[m1 * 1024 + ((cA ^ (m1 & 7)) << 3)];
        accA = __builtin_amdgcn_mfma_f32_16x16x32_bf16(a0, bfr, accA, 0, 0, 0);
        accB = __builtin_amdgcn_mfma_f32_16x16x32_bf16(a1, bfr, accB, 0, 0, 0);
    }

    __syncthreads();                       // all hs reads done; alias as gates
    float* gs = (float*)hs;                // gs[(gate*32+row)*16 + col], 8KB
    #pragma unroll
    for (int r = 0; r < 4; ++r) {
        int row = (lane >> 4) * 4 + r;     // C/D: row=(lane>>4)*4+reg, col=lane&15
        gs[(wave * 32 + row) * 16 + n]        = accA[r];
        gs[(wave * 32 + row + 16) * 16 + n]   = accB[r];
    }
    __syncthreads();

    #pragma unroll
    for (int e = tid; e < 512; e += 256) {
        int b = e >> 4, col = e & 15;
        int hcol = c0 + col;
        long pbase = (long)t * 131072 + b * 4096 + hcol;
        float gi = gs[(0 * 32 + b) * 16 + col] + (float)P[pbase];
        float gf = gs[(1 * 32 + b) * 16 + col] + (float)P[pbase + 1024];
        float gg = gs[(2 * 32 + b) * 16 + col] + (float)P[pbase + 2048];
        float go = gs[(3 * 32 + b) * 16 + col] + (float)P[pbase + 3072];
        float ig = 1.f / (1.f + __expf(-gi));
        float fg = 1.f / (1.f + __expf(-gf));
        float g  = tanhf(gg);
        float og = 1.f / (1.f + __expf(-go));
        float cold = cbuf[b * 1024 + hcol];
        float cnew = fg * cold + ig * g;
        float hnew = og * tanhf(cnew);
        cbuf[b * 1024 + hcol] = cnew;
        hout[b * 1024 + hcol] = (bf16)hnew;
        out[(long)b * RES_STRIDE + (long)t * 1024 + hcol] = hnew;
    }
}

// ---------- write hT (= res[:,510,:]) and cT to output tail ----------
__global__ void finalize_k(const float* __restrict__ cbuf, float* __restrict__ out) {
    int e = blockIdx.x * blockDim.x + threadIdx.x;
    if (e < 32768) {
        int b = e >> 10, col = e & 1023;
        out[HT_OFF + e] = out[(long)b * RES_STRIDE + 510 * 1024 + col];
        out[CT_OFF + e] = cbuf[e];
    }
}

extern "C" void kernel_launch(void* const* d_in, const int* in_sizes, int n_in,
                              void* d_out, int out_size, void* d_ws, size_t ws_size,
                              hipStream_t stream) {
    const int*   tgt  = (const int*)d_in[0];
    const float* h0   = (const float*)d_in[1];
    const float* c0   = (const float*)d_in[2];
    // d_in[3] encoder_outputs, d_in[4] src_lengths: unused by reference
    const float* embT = (const float*)d_in[5];
    const float* wih  = (const float*)d_in[6];
    const float* whh  = (const float*)d_in[7];
    const float* bih  = (const float*)d_in[8];
    const float* bhh  = (const float*)d_in[9];
    float* out = (float*)d_out;

    char* ws = (char*)d_ws;
    bf16*  P    = (bf16*)(ws);                 // 511*32*4096 bf16 = 133,955,584 B
    bf16*  embB = (bf16*)(ws + 133955584);     // 32000*1024 bf16  =  65,536,000 B
    bf16*  wihB = (bf16*)(ws + 199491584);     // 4096*1024 bf16   =   8,388,608 B
    bf16*  whhB = (bf16*)(ws + 207880192);     // 4096*1024 bf16   =   8,388,608 B
    bf16*  hA   = (bf16*)(ws + 216268800);     // 32*1024 bf16
    bf16*  hB   = (bf16*)(ws + 216334336);     // 32*1024 bf16
    float* cbuf = (float*)(ws + 216399872);    // 32*1024 fp32

    cvt_kernel<<<32000, 256, 0, stream>>>(embT, embB, 32768000 / 4);
    cvt_kernel<<<4096, 256, 0, stream>>>(wih, wihB, 4194304 / 4);
    cvt_kernel<<<4096, 256, 0, stream>>>(whh, whhB, 4194304 / 4);
    init_state<<<128, 256, 0, stream>>>(h0, c0, hA, cbuf);

    dim3 g(32, 128);   // N/128 x ceil(M/128)
    gemm_xproj<<<g, 256, 0, stream>>>(tgt, embB, wihB, bih, bhh, P);

    for (int t = 0; t < 511; ++t) {
        const bf16* hin = (t & 1) ? hB : hA;
        bf16*       ho  = (t & 1) ? hA : hB;
        lstm_step<<<64, 256, 0, stream>>>(P, whhB, hin, ho, cbuf, out, t);
    }
    finalize_k<<<128, 256, 0, stream>>>(cbuf, out);
}